// Round 1
// baseline (168.297 us; speedup 1.0000x reference)
//
#include <hip/hip_runtime.h>

#define B_ 4096
#define T_ 1024
#define H_ 15

// ===== Split-dot RNN step =====
// Each batch uses TWO 16-lane DPP rows (a quadrant pair l <-> l+32).
// half0 (lanes 0-31), lane m: accumulates rows m's terms c in {m-7..m}
//   via row_ror:0..7 (ror:0 is the plain fma seeded with bs).
// half1 (lanes 32-63), lane j: accumulates row p=(j+8)&15's terms
//   c in {j-7..j} = {p+1..p+8}  -- exact complement -- with the SAME
//   rotation controls 0..7 (weights select the shifted row).
// Combine: P holds [P0|P1]. mov P2=P is avoided by computing the tree sum
// twice; v_permlane32_swap_b32 P,P2 exchanges P.hi <-> P2.lo giving
// P=[P0|P0], P2=[P1|P1]; Z = dpp_ror8(P2) re-aligns half1 partials to
// row=lane; aF = P + Z is the full pre-activation in ALL 64 lanes.
// State u = 1/(exp2(a)+1), h = 1-2u (never materialized).
// Head fold: row 15 is the output head: half0 lane15 carries rotations
// giving c in {8..15} (c=15 weight 0) with bias C = b_lin + sum(w_lin);
// half1 lane7 carries c in {0..7}. aF[lane15] = out[t-1] (one-step
// delayed retirement, staged in osta like before).
// bs (x*w_ih + bias) for step t+1 is computed inside step t's combine
// gap (also serves as a hazard spacer). half1: wih2=bias2=0 -> bs=0.
//
// Hazard bookkeeping:
//  - rcp(u) -> next step's DPP read of u: tail s_nop 1 (2 wait states).
//  - same-chain fmac spacing >= 3 instructions (4 chains of 2).
//  - VALU write -> permlane/DPP read: s_nop 1 before swap and before
//    the ror8 mov_dpp.
//  - trans -> consumer covered by s_nop 0.
#define STEP(XTN, ODST)                                                       \
  do {                                                                        \
    float c1_, c2_, c3_, c4_, t12_, t34_, P_, P2_, Z_, e_;                    \
    asm("v_mul_f32_dpp %[c1], %[u], %[w1] row_ror:1 row_mask:0xf bank_mask:0xf\n\t" \
        "v_fma_f32 %[c2], %[u], %[w0], %[bs]\n\t"                             \
        "v_mul_f32_dpp %[c3], %[u], %[w3] row_ror:3 row_mask:0xf bank_mask:0xf\n\t" \
        "v_mul_f32_dpp %[c4], %[u], %[w2] row_ror:2 row_mask:0xf bank_mask:0xf\n\t" \
        "v_fmac_f32_dpp %[c1], %[u], %[w5] row_ror:5 row_mask:0xf bank_mask:0xf\n\t" \
        "v_fmac_f32_dpp %[c2], %[u], %[w4] row_ror:4 row_mask:0xf bank_mask:0xf\n\t" \
        "v_fmac_f32_dpp %[c3], %[u], %[w7] row_ror:7 row_mask:0xf bank_mask:0xf\n\t" \
        "v_fmac_f32_dpp %[c4], %[u], %[w6] row_ror:6 row_mask:0xf bank_mask:0xf\n\t" \
        "v_fma_f32 %[bs], %[xtn], %[wih], %[bias]\n\t"                        \
        "v_add_f32 %[t12], %[c1], %[c2]\n\t"                                  \
        "v_add_f32 %[t34], %[c3], %[c4]\n\t"                                  \
        "v_add_f32 %[P], %[t12], %[t34]\n\t"                                  \
        "v_add_f32 %[P2], %[t12], %[t34]\n\t"                                 \
        "s_nop 1\n\t"                                                         \
        "v_permlane32_swap_b32 %[P], %[P2]\n\t"                               \
        "s_nop 1\n\t"                                                         \
        "v_mov_b32_dpp %[Z], %[P2] row_ror:8 row_mask:0xf bank_mask:0xf\n\t"  \
        "v_add_f32 %[aF], %[P], %[Z]\n\t"                                     \
        "v_exp_f32 %[e], %[aF]\n\t"                                           \
        "s_nop 0\n\t"                                                         \
        "v_add_f32 %[e], 1.0, %[e]\n\t"                                       \
        "v_rcp_f32 %[u], %[e]\n\t"                                            \
        "s_nop 1\n\t"                                                         \
        : [u] "+v"(u), [bs] "+v"(bs), [aF] "=&v"(ODST),                       \
          [c1] "=&v"(c1_), [c2] "=&v"(c2_), [c3] "=&v"(c3_), [c4] "=&v"(c4_), \
          [t12] "=&v"(t12_), [t34] "=&v"(t34_), [P] "=&v"(P_),                \
          [P2] "=&v"(P2_), [Z] "=&v"(Z_), [e] "=&v"(e_)                       \
        : [xtn] "v"(XTN), [wih] "v"(wih2), [bias] "v"(bias2),                 \
          [w0] "v"(wr2[0]), [w1] "v"(wr2[1]), [w2] "v"(wr2[2]),               \
          [w3] "v"(wr2[3]), [w4] "v"(wr2[4]), [w5] "v"(wr2[5]),               \
          [w6] "v"(wr2[6]), [w7] "v"(wr2[7]));                                \
  } while (0)

// Pipeline position K (0..31): runs step t+K; XV is x for step t+K+1
// (feeds the bs-prefetch inside the asm). Lane-15/31 tree value is
// out[t+K-1] -> staged at (K-1)&3; finished 4-pack stored at K%4==0;
// one x buffer refilled per 4 steps.
#define POS(K, XV)                                                            \
  do {                                                                        \
    float o_;                                                                 \
    STEP(XV, o_);                                                             \
    osta[((K) + 3) & 3] = o_;                                                 \
    if (((K) & 3) == 0) {                                                     \
      if ((K) > 0 || t > 0) {                                                 \
        if ((tid & 47) == 15)                                                 \
          *(float4*)(ob + t + (K) - 4) =                                      \
              make_float4(osta[0], osta[1], osta[2], osta[3]);                \
      }                                                                       \
    }                                                                         \
    if (((K) & 3) == 3) {                                                     \
      int _tn = t + 32 + (((K) >> 2) << 2);                                   \
      if (_tn >= T_) _tn = 0; /* clamped dummy refill near the end */         \
      qq[(K) >> 2] = *(const float4*)(xb + _tn);                              \
    }                                                                         \
  } while (0)

// 32 lanes/batch (split dot), 2 batches/wave, 2048 waves = 2 waves/SIMD.
__global__ __attribute__((amdgpu_flat_work_group_size(256, 256),
                          amdgpu_waves_per_eu(2, 2)))
void rnn_tanh_kernel(
    const float* __restrict__ x, const float* __restrict__ w_ih,
    const float* __restrict__ w_hh, const float* __restrict__ b_ih,
    const float* __restrict__ b_hh, const float* __restrict__ w_lin,
    const float* __restrict__ b_lin, float* __restrict__ out) {
  const int tid = threadIdx.x;
  const int m = tid & 15;            // lane within DPP row
  const int r = (tid >> 4) & 3;      // quadrant
  const int half = r >> 1;           // dot-half
  const int q = r & 1;               // batch within wave
  const int b = blockIdx.x * 8 + ((tid >> 6) << 1) + q;

  const float S = 2.8853900817779268f;  // 2*log2(e)

  // out = C - 2*sum(w_lin*u), C = b_lin + sum(w_lin).
  float wsum = b_lin[0];
  for (int j = 0; j < H_; ++j) wsum += w_lin[j];
  const float C = wsum;

  // This lane accumulates partials for row p with rotations 0..7.
  const int p = half ? ((m + 8) & 15) : m;
  float wr2[8];
#pragma unroll
  for (int n = 0; n < 8; ++n) {
    const int c = (m - n) & 15;
    float w = 0.0f;
    if (c < H_) {
      if (p < H_) w = -2.0f * S * w_hh[p * H_ + c];
      else        w = -2.0f * w_lin[c];   // head row
    }
    wr2[n] = w;
  }
  float rowsum = 0.0f;
  if (m < H_)
    for (int j = 0; j < H_; ++j) rowsum += w_hh[m * H_ + j];
  // bias / x-projection enter ONCE, through half0 only.
  const float wih2 = (half == 0 && m < H_) ? S * w_ih[m] : 0.0f;
  const float bias2 =
      (half == 0) ? ((m < H_) ? S * (b_ih[m] + b_hh[m] + rowsum) : C) : 0.0f;

  const float* xb = x + (size_t)b * T_;
  float* ob = out + (size_t)b * T_;

  float u = 0.5f;  // h=0 -> u=0.5 (u[15] garbage never consumed: c=15 weights are 0)
  asm("s_nop 1" : "+v"(u));  // guard: >=2 wait states before first DPP read
  float osta[4];             // output staging (constant-indexed -> registers)

  // 8-buffer x software pipeline.
  float4 qq[8];
#pragma unroll
  for (int j = 0; j < 8; ++j) qq[j] = *(const float4*)(xb + 4 * j);

  // bs for step 0 (half1 lanes: 0*x+0 = 0).
  float bs = fmaf(qq[0].x, wih2, bias2);

  for (int t = 0; t < T_; t += 32) {
    POS(0,  qq[0].y); POS(1,  qq[0].z); POS(2,  qq[0].w); POS(3,  qq[1].x);
    POS(4,  qq[1].y); POS(5,  qq[1].z); POS(6,  qq[1].w); POS(7,  qq[2].x);
    POS(8,  qq[2].y); POS(9,  qq[2].z); POS(10, qq[2].w); POS(11, qq[3].x);
    POS(12, qq[3].y); POS(13, qq[3].z); POS(14, qq[3].w); POS(15, qq[4].x);
    POS(16, qq[4].y); POS(17, qq[4].z); POS(18, qq[4].w); POS(19, qq[5].x);
    POS(20, qq[5].y); POS(21, qq[5].z); POS(22, qq[5].w); POS(23, qq[6].x);
    POS(24, qq[6].y); POS(25, qq[6].z); POS(26, qq[6].w); POS(27, qq[7].x);
    POS(28, qq[7].y); POS(29, qq[7].z); POS(30, qq[7].w); POS(31, qq[0].x);
  }

  // Epilogue: one extra STEP (dummy x; head bias path is x-independent
  // since wih2=0 on lane 15) -- retires out[T-1]; store last 4-pack.
  {
    float o_;
    STEP(0.0f, o_);
    osta[3] = o_;
    if ((tid & 47) == 15)
      *(float4*)(ob + T_ - 4) = make_float4(osta[0], osta[1], osta[2], osta[3]);
  }
}

extern "C" void kernel_launch(void* const* d_in, const int* in_sizes, int n_in,
                              void* d_out, int out_size, void* d_ws, size_t ws_size,
                              hipStream_t stream) {
  (void)in_sizes; (void)n_in; (void)out_size; (void)d_ws; (void)ws_size;
  rnn_tanh_kernel<<<B_ / 8, 256, 0, stream>>>(
      (const float*)d_in[0], (const float*)d_in[1], (const float*)d_in[2],
      (const float*)d_in[3], (const float*)d_in[4], (const float*)d_in[5],
      (const float*)d_in[6], (float*)d_out);
}

// Round 2
// 140.390 us; speedup vs baseline: 1.1988x; 1.1988x over previous
//
#include <hip/hip_runtime.h>

#define B_ 4096
#define T_ 1024
#define H_ 15

// ===== Whole RNN step as ONE hand-scheduled asm block (R2: short-chain) =====
// State: u = 1/(exp2(a)+1)  (h = 1-2u, never materialized).
// Head-fold: lane 15 (pad row) carries the output head: wr15[n] =
// -2*w_lin[(15-n)&15], bias15 = C = b_lin + sum(w_lin) — so lane 15's full
// pre-activation sum (tree + diag) = C - 2*sum(w_lin*u_prev) = out[t-1]
// (one-step-delayed retirement, staged in osta).  u[15] garbage, never
// consumed (every lane's c=15 weight is 0; |out| small so 2^out finite).
//
// R2 chain surgery vs R0:
//  - 3 DPP chains x5 (rot 1..15) + diagonal as a depth-1 plain fma seeded
//    with bs  ->  only ONE tree add after the last DPP chain.
//  - exp-split: 2^a = 2^tree * 2^diag; e = fma(eT, eD, 1.0) folds the
//    "+1.0" add into the mul; eD computes inside eT's shadow.
//  - s_nops replaced by useful spacers: o = tree + diag (output capture,
//    eT 1-wait-state) and next-step bs prefetch (rcp shadow); one s_nop 0
//    remains as the 2nd DPP wait state before the next block's muls.
//
// Hazard bookkeeping:
//  - DPP-source (u) read needs 2 wait states after rcp write: bs-fma +
//    s_nop 0 in-tail (+ any inter-block glue = margin).
//  - same-chain DPP fmac spacing = 3 instructions (A/B/C round-robin).
//  - trans->consumer 1 wait state: eT->fma gap=1 (o-add), eD->fma gap=3.
#define STEP(XTN, ODST)                                                       \
  do {                                                                        \
    float cA_, cB_, cC_, d_, tAB_, tT_, eD_, eT_, e_;                         \
    asm("v_mul_f32_dpp %[cA], %[u], %[w1] row_ror:1 row_mask:0xf bank_mask:0xf\n\t"   \
        "v_mul_f32_dpp %[cB], %[u], %[w2] row_ror:2 row_mask:0xf bank_mask:0xf\n\t"   \
        "v_mul_f32_dpp %[cC], %[u], %[w3] row_ror:3 row_mask:0xf bank_mask:0xf\n\t"   \
        "v_fmac_f32_dpp %[cA], %[u], %[w4] row_ror:4 row_mask:0xf bank_mask:0xf\n\t"  \
        "v_fmac_f32_dpp %[cB], %[u], %[w5] row_ror:5 row_mask:0xf bank_mask:0xf\n\t"  \
        "v_fmac_f32_dpp %[cC], %[u], %[w6] row_ror:6 row_mask:0xf bank_mask:0xf\n\t"  \
        "v_fmac_f32_dpp %[cA], %[u], %[w7] row_ror:7 row_mask:0xf bank_mask:0xf\n\t"  \
        "v_fmac_f32_dpp %[cB], %[u], %[w8] row_ror:8 row_mask:0xf bank_mask:0xf\n\t"  \
        "v_fmac_f32_dpp %[cC], %[u], %[w9] row_ror:9 row_mask:0xf bank_mask:0xf\n\t"  \
        "v_fmac_f32_dpp %[cA], %[u], %[w10] row_ror:10 row_mask:0xf bank_mask:0xf\n\t" \
        "v_fmac_f32_dpp %[cB], %[u], %[w11] row_ror:11 row_mask:0xf bank_mask:0xf\n\t" \
        "v_fmac_f32_dpp %[cC], %[u], %[w12] row_ror:12 row_mask:0xf bank_mask:0xf\n\t" \
        "v_fmac_f32_dpp %[cA], %[u], %[w13] row_ror:13 row_mask:0xf bank_mask:0xf\n\t" \
        "v_fmac_f32_dpp %[cB], %[u], %[w14] row_ror:14 row_mask:0xf bank_mask:0xf\n\t" \
        "v_fmac_f32_dpp %[cC], %[u], %[w15] row_ror:15 row_mask:0xf bank_mask:0xf\n\t" \
        "v_fma_f32 %[d], %[u], %[w0], %[bs]\n\t"                              \
        "v_add_f32 %[tAB], %[cA], %[cB]\n\t"                                  \
        "v_exp_f32 %[eD], %[d]\n\t"                                           \
        "v_add_f32 %[tT], %[tAB], %[cC]\n\t"                                  \
        "v_exp_f32 %[eT], %[tT]\n\t"                                          \
        "v_add_f32 %[o], %[tT], %[d]\n\t"                                     \
        "v_fma_f32 %[e], %[eT], %[eD], 1.0\n\t"                               \
        "v_rcp_f32 %[u], %[e]\n\t"                                            \
        "v_fma_f32 %[bs], %[xtn], %[wih], %[bias]\n\t"                        \
        "s_nop 0\n\t"                                                         \
        : [u] "+v"(u), [bs] "+v"(bs), [o] "=&v"(ODST),                        \
          [cA] "=&v"(cA_), [cB] "=&v"(cB_), [cC] "=&v"(cC_), [d] "=&v"(d_),   \
          [tAB] "=&v"(tAB_), [tT] "=&v"(tT_), [eD] "=&v"(eD_),                \
          [eT] "=&v"(eT_), [e] "=&v"(e_)                                      \
        : [xtn] "v"(XTN), [wih] "v"(wih2), [bias] "v"(bias2),                 \
          [w0] "v"(wr[0]), [w1] "v"(wr[1]), [w2] "v"(wr[2]),                  \
          [w3] "v"(wr[3]), [w4] "v"(wr[4]), [w5] "v"(wr[5]),                  \
          [w6] "v"(wr[6]), [w7] "v"(wr[7]), [w8] "v"(wr[8]),                  \
          [w9] "v"(wr[9]), [w10] "v"(wr[10]), [w11] "v"(wr[11]),              \
          [w12] "v"(wr[12]), [w13] "v"(wr[13]), [w14] "v"(wr[14]),            \
          [w15] "v"(wr[15]));                                                 \
  } while (0)

// Pipeline position K (0..31): runs step t+K; XV is x for step t+K+1
// (feeds the in-asm bs prefetch). Lane-15 sum = out[t+K-1] -> staged at
// (K-1)&3; finished 4-pack stored at K%4==0 (skip the first, garbage,
// retirement); one x buffer refilled per 4 steps (refill-to-use = 28 steps).
#define POS(K, XV)                                                            \
  do {                                                                        \
    float o_;                                                                 \
    STEP(XV, o_);                                                             \
    osta[((K) + 3) & 3] = o_;                                                 \
    if (((K) & 3) == 0) {                                                     \
      if ((K) > 0 || t > 0) {                                                 \
        if (m == 15)                                                          \
          *(float4*)(ob + t + (K) - 4) =                                      \
              make_float4(osta[0], osta[1], osta[2], osta[3]);                \
      }                                                                       \
    }                                                                         \
    if (((K) & 3) == 3) {                                                     \
      int _tn = t + 32 + (((K) >> 2) << 2);                                   \
      if (_tn >= T_) _tn = 0; /* clamped dummy refill near the end */         \
      qq[(K) >> 2] = *(const float4*)(xb + _tn);                              \
    }                                                                         \
  } while (0)

// 16 lanes/batch, 4 batches/wave, 1024 waves = 1 wave/SIMD.
__global__ __attribute__((amdgpu_flat_work_group_size(256, 256),
                          amdgpu_waves_per_eu(1, 1)))
void rnn_tanh_kernel(
    const float* __restrict__ x, const float* __restrict__ w_ih,
    const float* __restrict__ w_hh, const float* __restrict__ b_ih,
    const float* __restrict__ b_hh, const float* __restrict__ w_lin,
    const float* __restrict__ b_lin, float* __restrict__ out) {
  const int tid = threadIdx.x;
  const int m = tid & 15;                      // hidden row (15 = head lane)
  const int b = blockIdx.x * 16 + (tid >> 4);  // batch index

  const float S = 2.8853900817779268f;         // 2*log2(e)

  // out = C - 2*sum(w_lin*u), C = b_lin + sum(w_lin).
  float wsum = b_lin[0];
  for (int j = 0; j < H_; ++j) wsum += w_lin[j];
  const float C = wsum;

  // Rotation-permuted weights (rot n reads u[(m-n)&15]).
  // Lanes 0..14: recurrence rows, scaled by -2S. Lane 15: head weights.
  float wr[16];
#pragma unroll
  for (int n = 0; n < 16; ++n) {
    const int c = (m - n) & 15;
    if (m < H_)
      wr[n] = (c < H_) ? -2.0f * S * w_hh[m * H_ + c] : 0.0f;
    else
      wr[n] = (c < H_) ? -2.0f * w_lin[c] : 0.0f;
  }
  float rowsum = 0.0f;
  if (m < H_)
    for (int j = 0; j < H_; ++j) rowsum += w_hh[m * H_ + j];
  const float wih2  = (m < H_) ? S * w_ih[m] : 0.0f;
  const float bias2 = (m < H_) ? S * (b_ih[m] + b_hh[m] + rowsum) : C;

  const float* xb = x + (size_t)b * T_;
  float* ob = out + (size_t)b * T_;

  float u = 0.5f;  // h=0 -> u=0.5 (lane 15's u is never consumed)
  asm("s_nop 1" : "+v"(u));  // guard: >=2 wait states before first DPP read
  float osta[4];             // output staging (constant-indexed -> registers)

  // 8-buffer x software pipeline.
  float4 qq[8];
#pragma unroll
  for (int j = 0; j < 8; ++j) qq[j] = *(const float4*)(xb + 4 * j);

  // bs for step 0 (prefetched pattern: STEP consumes current bs, computes next).
  float bs = fmaf(qq[0].x, wih2, bias2);

  for (int t = 0; t < T_; t += 32) {
    POS(0,  qq[0].y); POS(1,  qq[0].z); POS(2,  qq[0].w); POS(3,  qq[1].x);
    POS(4,  qq[1].y); POS(5,  qq[1].z); POS(6,  qq[1].w); POS(7,  qq[2].x);
    POS(8,  qq[2].y); POS(9,  qq[2].z); POS(10, qq[2].w); POS(11, qq[3].x);
    POS(12, qq[3].y); POS(13, qq[3].z); POS(14, qq[3].w); POS(15, qq[4].x);
    POS(16, qq[4].y); POS(17, qq[4].z); POS(18, qq[4].w); POS(19, qq[5].x);
    POS(20, qq[5].y); POS(21, qq[5].z); POS(22, qq[5].w); POS(23, qq[6].x);
    POS(24, qq[6].y); POS(25, qq[6].z); POS(26, qq[6].w); POS(27, qq[7].x);
    POS(28, qq[7].y); POS(29, qq[7].z); POS(30, qq[7].w); POS(31, qq[0].x);
  }

  // Epilogue: one extra STEP (dummy x feeds only the dead bs prefetch) —
  // its lane-15 sum reads the final u_{T-1}, producing out[T-1]; complete
  // and store the last 4-pack.
  {
    float o_;
    STEP(0.0f, o_);
    osta[3] = o_;
    if (m == 15)
      *(float4*)(ob + T_ - 4) = make_float4(osta[0], osta[1], osta[2], osta[3]);
  }
}

extern "C" void kernel_launch(void* const* d_in, const int* in_sizes, int n_in,
                              void* d_out, int out_size, void* d_ws, size_t ws_size,
                              hipStream_t stream) {
  (void)in_sizes; (void)n_in; (void)out_size; (void)d_ws; (void)ws_size;
  rnn_tanh_kernel<<<B_ / 16, 256, 0, stream>>>(
      (const float*)d_in[0], (const float*)d_in[1], (const float*)d_in[2],
      (const float*)d_in[3], (const float*)d_in[4], (const float*)d_in[5],
      (const float*)d_in[6], (float*)d_out);
}